// Round 15
// baseline (404.541 us; speedup 1.0000x reference)
//
#include <hip/hip_runtime.h>
#include <hip/hip_bf16.h>

#define B_SZ 16
#define C_IN 256
#define N_SP 2304
#define K_INT 128
#define NTILE 36  // q-tiles of 64
#define MT 32     // key/value m-tile
#define MITER 72  // N_SP / MT

typedef __attribute__((ext_vector_type(8))) short short8;
typedef __attribute__((ext_vector_type(4))) float f32x4;

// packed fp32x2 -> bf16x2 (v_cvt_pk_bf16_f32, RNE)
__device__ inline unsigned pk_bf16(float a, float b) {
  float2 f; f.x = a; f.y = b;
  __hip_bfloat162 h = __float22bfloat162_rn(f);
  unsigned u;
  __builtin_memcpy(&u, &h, sizeof(u));
  return u;
}

// inline f32 weight row -> bf16 A-fragment (bit-identical to wcvt's RNE)
__device__ inline short8 ldw_bf16(const float* __restrict__ W, int k, int c0) {
  const float* wp = W + (size_t)k * C_IN + c0;
  float4 w0 = ((const float4*)wp)[0];
  float4 w1 = ((const float4*)wp)[1];
  unsigned u[4];
  u[0] = pk_bf16(w0.x, w0.y); u[1] = pk_bf16(w0.z, w0.w);
  u[2] = pk_bf16(w1.x, w1.y); u[3] = pk_bf16(w1.z, w1.w);
  short8 a;
  __builtin_memcpy(&a, u, sizeof(a));
  return a;
}

// ---------------------------------------------------------------------------
// Projection v8 (byte-identical to R14, passed at absmax 4.88e-4).
// ---------------------------------------------------------------------------
__global__ __launch_bounds__(256) void proj_kernel(
    const float* __restrict__ x,
    const float* __restrict__ theta_w, const float* __restrict__ theta_b,
    const float* __restrict__ phi_w,   const float* __restrict__ phi_b,
    short* __restrict__ Qt, short* __restrict__ Kt, short* __restrict__ Gbf)
{
  __shared__ __align__(16) char Xs[32768];  // [64 n][512 B] swizzled

  const int b  = blockIdx.x / NTILE;
  const int n0 = (blockIdx.x % NTILE) * 64;
  const int t  = threadIdx.x;
  const int wave = t >> 6, lane = t & 63;
  const int col = lane & 15, quad = lane >> 4;

  // ---- stage: coalesced loads, in-register 4x4 pack, b64 LDS writes ----
  {
    const int tq = t >> 4;   // c-row group
    const int a  = t & 15;   // n-segment (4 floats)
    const float* xs = x + ((size_t)b * C_IN + tq * 4) * N_SP + n0 + a * 4;
    short* gs = Gbf + ((size_t)b * C_IN + tq * 4) * N_SP + n0 + a * 4;
#pragma unroll
    for (int s = 0; s < 4; ++s) {  // c-base = s*64 + tq*4
      unsigned us[4][2];
#pragma unroll
      for (int r = 0; r < 4; ++r) {
        float4 v = *(const float4*)(xs + ((size_t)s * 64 + r) * N_SP);
        us[r][0] = pk_bf16(v.x, v.y);
        us[r][1] = pk_bf16(v.z, v.w);
        uint2 u; u.x = us[r][0]; u.y = us[r][1];
        *(uint2*)(gs + ((size_t)s * 64 + r) * N_SP) = u;
      }
      const int chunk = 8 * s + (tq >> 1);
      const int half8 = (tq & 1) * 8;
#pragma unroll
      for (int j = 0; j < 4; ++j) {
        const int w = j >> 1;
        unsigned w0, w1;
        if ((j & 1) == 0) {
          w0 = (us[0][w] & 0xffffu) | (us[1][w] << 16);
          w1 = (us[2][w] & 0xffffu) | (us[3][w] << 16);
        } else {
          w0 = (us[0][w] >> 16) | (us[1][w] & 0xffff0000u);
          w1 = (us[2][w] >> 16) | (us[3][w] & 0xffff0000u);
        }
        const int n = 4 * a + j;
        const int msk = (n ^ a) & 7;  // (n ^ (n>>2)) & 7
        uint2 u; u.x = w0; u.y = w1;
        *(uint2*)(Xs + n * 512 + ((chunk ^ msk) << 4) + half8) = u;
      }
    }
  }
  __syncthreads();

  // ---- GEMM: acc[p][kr][j] over 8 c-slices, weights converted inline ----
  f32x4 acc[2][2][4];
#pragma unroll
  for (int p = 0; p < 2; ++p)
#pragma unroll
    for (int kr = 0; kr < 2; ++kr)
#pragma unroll
      for (int j = 0; j < 4; ++j) {
        acc[p][kr][j][0] = 0.f; acc[p][kr][j][1] = 0.f;
        acc[p][kr][j][2] = 0.f; acc[p][kr][j][3] = 0.f;
      }

  int rmsk[4];
#pragma unroll
  for (int j = 0; j < 4; ++j) {
    const int n = 16 * j + col;
    rmsk[j] = (n ^ (n >> 2)) & 7;
  }

#pragma unroll
  for (int cs = 0; cs < 8; ++cs) {
    const int c0 = cs * 32;
    short8 afr[2][2];
#pragma unroll
    for (int p = 0; p < 2; ++p)
#pragma unroll
      for (int kr = 0; kr < 2; ++kr) {
        const int k = wave * 32 + kr * 16 + col;
        afr[p][kr] = ldw_bf16(p ? phi_w : theta_w, k, c0 + quad * 8);
      }
#pragma unroll
    for (int j = 0; j < 4; ++j) {
      const int chunk = 4 * cs + quad;
      short8 bfr = *(const short8*)(Xs + (16 * j + col) * 512 +
                                    ((chunk ^ rmsk[j]) << 4));
#pragma unroll
      for (int p = 0; p < 2; ++p)
#pragma unroll
        for (int kr = 0; kr < 2; ++kr)
          acc[p][kr][j] = __builtin_amdgcn_mfma_f32_16x16x32_bf16(
              afr[p][kr], bfr, acc[p][kr][j], 0, 0, 0);
    }
  }
  __syncthreads();  // Xs reads done; reuse as epilogue bounce buffer

  // ---- epilogue: bias, LDS bounce, coalesced b128 stores ----
  short* PB = (short*)Xs;  // [64 n][128 k] shorts, granule-swizzled
#pragma unroll
  for (int p = 0; p < 2; ++p) {
    const float* bias = p ? phi_b : theta_b;
    short* dst0 = p ? Kt : Qt;
#pragma unroll
    for (int kr = 0; kr < 2; ++kr) {
      const int k0 = wave * 32 + kr * 16 + quad * 4;
      float4 bv = *(const float4*)(bias + k0);
      const int g = wave * 8 + kr * 4 + quad;
#pragma unroll
      for (int j = 0; j < 4; ++j) {
        const int nloc = j * 16 + col;
        f32x4 v = acc[p][kr][j];
        uint2 sv;
        sv.x = pk_bf16(v[0] + bv.x, v[1] + bv.y);
        sv.y = pk_bf16(v[2] + bv.z, v[3] + bv.w);
        const int gp = g ^ (nloc & 7) ^ (((nloc >> 3) & 1) << 3);
        *(uint2*)(PB + nloc * 128 + gp * 4) = sv;
      }
    }
    __syncthreads();
    {
      const int nloc = t >> 2, kseg = t & 3;
      const int xb = ((nloc >> 3) & 1) << 3;
      uint2 r8[8];
#pragma unroll
      for (int i = 0; i < 8; ++i) {
        const int gp = (kseg * 8 + i) ^ (nloc & 7) ^ xb;
        r8[i] = *(const uint2*)(PB + nloc * 128 + gp * 4);
      }
      short* dst = dst0 + ((size_t)b * N_SP + n0 + nloc) * K_INT + kseg * 32;
#pragma unroll
      for (int i2 = 0; i2 < 4; ++i2) {
        uint4 u;
        u.x = r8[2 * i2].x;     u.y = r8[2 * i2].y;
        u.z = r8[2 * i2 + 1].x; u.w = r8[2 * i2 + 1].y;
        *(uint4*)(dst + i2 * 8) = u;
      }
    }
    __syncthreads();  // before p=1 overwrites PB
  }
}

// ---------------------------------------------------------------------------
// Flash attention v11: R4 schedule with K moved from LDS to registers.
//  - K A-fragments are contiguous 16B global loads (R3 proved correctness);
//    single-buffered kf[8], re-issued for tile i+1 RIGHT AFTER QK(i) consumes
//    them -> ~full-iteration lead, drained collectively at the barrier --
//    the exact pattern R4's G path has run at 147us for 6 rounds.
//  - DS ops/wave/iter 15 -> 5 (P exchange only, measured-0-conflict);
//    Kl/KW/KR gone; LDS 25KB -> 8.5KB.
//  - 4x K L2-read redundancy (waves share nothing): 1.3GB @ L2 ~ 9 TB/s,
//    far under the 34.5 TB/s ceiling.
//  - barrier structure, G path, P path, epilogue: byte-identical to R4.
// ---------------------------------------------------------------------------
__global__ __launch_bounds__(256) void attn_kernel(
    const short* __restrict__ Qt, const short* __restrict__ Kt,
    const short* __restrict__ Gbf, float* __restrict__ out)
{
  __shared__ __align__(16) short Pblob[2][4][64][8];  // [buf][wave][lane][8]
  __shared__ float l_lds[64];

  const int b   = blockIdx.x / NTILE;
  const int qn0 = (blockIdx.x % NTILE) * 64;
  const int t = threadIdx.x;
  const int wave = t >> 6, lane = t & 63;
  const int col = lane & 15, quad = lane >> 4;

  const short* Ktb = Kt  + (size_t)b * N_SP * K_INT;
  const short* Gb  = Gbf + (size_t)b * C_IN * N_SP;

  // Q fragments in registers for the whole loop (B-operand layout: col=q)
  short8 qf[4];
  {
    const short* qb = Qt + ((size_t)b * N_SP + qn0 + wave * 16 + col) * K_INT + quad * 8;
#pragma unroll
    for (int kk = 0; kk < 4; ++kk) qf[kk] = *(const short8*)(qb + kk * 32);
  }

  f32x4 yacc[4][4];  // [q-tile][c-tile]
#pragma unroll
  for (int i = 0; i < 4; ++i)
#pragma unroll
    for (int j = 0; j < 4; ++j) {
      yacc[i][j][0] = 0.f; yacc[i][j][1] = 0.f;
      yacc[i][j][2] = 0.f; yacc[i][j][3] = 0.f;
    }
  f32x4 lacc;
  lacc[0] = 0.f; lacc[1] = 0.f; lacc[2] = 0.f; lacc[3] = 0.f;

  short8 ones;
#pragma unroll
  for (int j = 0; j < 8; ++j) ones[j] = (short)0x3F80;  // bf16 1.0

  const float SC2 = 0.12754859f;  // (1/sqrt(128)) * log2(e)

  // ---- per-lane operand bases (fragments are contiguous 16B) ----
  const short* kbase = Ktb + col * K_INT + quad * 8;                      // K rows m0+col / +16
  const short* gbase = Gb + ((size_t)(wave * 64 + col)) * N_SP + quad * 8;  // G rows c

  // ---- prologue: kf <- K tile 0 (regs); gA <- G tile 0 ----
  short8 kf[8];
#pragma unroll
  for (int kk = 0; kk < 4; ++kk) {
    kf[2 * kk]     = *(const short8*)(kbase + kk * 32);
    kf[2 * kk + 1] = *(const short8*)(kbase + 2048 + kk * 32);
  }
  short8 gA[4], gB[4];
#pragma unroll
  for (int ct = 0; ct < 4; ++ct)
    gA[ct] = *(const short8*)(gbase + (size_t)ct * 16 * N_SP);

#define SUBITER(MTV, CUR, GC, GN)                                              \
  {                                                                            \
    /* 1. QK: S = K(tile MTV) x Q  (A-frags from registers) */                 \
    f32x4 s0, s1;                                                              \
    s0[0] = 0.f; s0[1] = 0.f; s0[2] = 0.f; s0[3] = 0.f;                        \
    s1[0] = 0.f; s1[1] = 0.f; s1[2] = 0.f; s1[3] = 0.f;                        \
    _Pragma("unroll")                                                          \
    for (int kk = 0; kk < 4; ++kk) {                                           \
      s0 = __builtin_amdgcn_mfma_f32_16x16x32_bf16(kf[2 * kk],     qf[kk],     \
                                                   s0, 0, 0, 0);               \
      s1 = __builtin_amdgcn_mfma_f32_16x16x32_bf16(kf[2 * kk + 1], qf[kk],     \
                                                   s1, 0, 0, 0);               \
    }                                                                          \
    /* 2. K loads for tile MTV+1 into kf (WAR after QK; ~1-iter lead, */       \
    /*    drained collectively at this iter's barrier, consumed next QK) */    \
    if ((MTV) + 1 < MITER) {                                                   \
      const short* kp = kbase + (size_t)((MTV) + 1) * 4096;                    \
      _Pragma("unroll")                                                        \
      for (int kk = 0; kk < 4; ++kk) {                                         \
        kf[2 * kk]     = *(const short8*)(kp + kk * 32);                       \
        kf[2 * kk + 1] = *(const short8*)(kp + 2048 + kk * 32);                \
      }                                                                        \
    }                                                                          \
    /* 3. softmax-lite + in-register transpose to A-fragment */                \
    unsigned u0 = pk_bf16(exp2f(s0[0] * SC2), exp2f(s0[1] * SC2));             \
    unsigned u1 = pk_bf16(exp2f(s0[2] * SC2), exp2f(s0[3] * SC2));             \
    unsigned u2 = pk_bf16(exp2f(s1[0] * SC2), exp2f(s1[1] * SC2));             \
    unsigned u3 = pk_bf16(exp2f(s1[2] * SC2), exp2f(s1[3] * SC2));             \
    asm("v_permlane32_swap_b32 %0, %1" : "+v"(u0), "+v"(u2));                  \
    asm("v_permlane32_swap_b32 %0, %1" : "+v"(u1), "+v"(u3));                  \
    asm("v_permlane16_swap_b32 %0, %1" : "+v"(u0), "+v"(u2));                  \
    asm("v_permlane16_swap_b32 %0, %1" : "+v"(u1), "+v"(u3));                  \
    unsigned uu[4] = {u0, u1, u2, u3};                                         \
    short8 pa; __builtin_memcpy(&pa, uu, 16);                                  \
    lacc = __builtin_amdgcn_mfma_f32_16x16x32_bf16(pa, ones, lacc, 0, 0, 0);   \
    /* 4. P exchange write (lane-linear, conflict-free) */                     \
    *(short8*)&Pblob[CUR][wave][lane][0] = pa;                                 \
    /* 5. G global prefetch: tile MTV+1 (consumed next iter's PV) */           \
    if ((MTV) + 1 < MITER) {                                                   \
      _Pragma("unroll")                                                        \
      for (int ct = 0; ct < 4; ++ct)                                           \
        GN[ct] = *(const short8*)(gbase + (size_t)ct * 16 * N_SP +             \
                                  ((MTV) + 1) * 32);                           \
    }                                                                          \
    __syncthreads();                                                           \
    /* 6. PV: Y[q][c] += P[q][m] G^T[m][c]  (G regs, P lane-linear) */         \
    _Pragma("unroll")                                                          \
    for (int qt = 0; qt < 4; ++qt) {                                           \
      short8 paq = *(const short8*)&Pblob[CUR][qt][lane][0];                   \
      _Pragma("unroll")                                                        \
      for (int ct = 0; ct < 4; ++ct)                                           \
        yacc[qt][ct] = __builtin_amdgcn_mfma_f32_16x16x32_bf16(                \
            paq, GC[ct], yacc[qt][ct], 0, 0, 0);                               \
    }                                                                          \
  }

  for (int mt2 = 0; mt2 < MITER / 2; ++mt2) {
    SUBITER(2 * mt2,     0, gA, gB)
    SUBITER(2 * mt2 + 1, 1, gB, gA)
  }
#undef SUBITER

  // ---- l exchange: wave w holds l[16w + quad*4 + r] in lacc[r] ----
  if (col == 0) {
#pragma unroll
    for (int r = 0; r < 4; ++r) l_lds[wave * 16 + quad * 4 + r] = lacc[r];
  }
  __syncthreads();

  // ---- epilogue: normalize and store out[b][c][n]; c = wave*64+ct*16+col ----
#pragma unroll
  for (int qt = 0; qt < 4; ++qt) {
    float4 lq = *(const float4*)&l_lds[qt * 16 + quad * 4];
    float4 iv;
    iv.x = 1.0f / lq.x; iv.y = 1.0f / lq.y; iv.z = 1.0f / lq.z; iv.w = 1.0f / lq.w;
    const int nb = qn0 + qt * 16 + quad * 4;
#pragma unroll
    for (int ct = 0; ct < 4; ++ct) {
      const int c = wave * 64 + ct * 16 + col;
      f32x4 v = yacc[qt][ct];
      float4 o;
      o.x = v[0] * iv.x; o.y = v[1] * iv.y; o.z = v[2] * iv.z; o.w = v[3] * iv.w;
      *(float4*)(out + ((size_t)b * C_IN + c) * N_SP + nb) = o;
    }
  }
}

extern "C" void kernel_launch(void* const* d_in, const int* in_sizes, int n_in,
                              void* d_out, int out_size, void* d_ws, size_t ws_size,
                              hipStream_t stream) {
  const float* x  = (const float*)d_in[0];
  const float* tw = (const float*)d_in[1];
  const float* tb = (const float*)d_in[2];
  const float* pw = (const float*)d_in[3];
  const float* pb = (const float*)d_in[4];
  float* out = (float*)d_out;

  // workspace: Qt (9.4MB) | Kt (9.4MB) | Gbf (18.9MB) = 37.75 MB total
  short* Qt  = (short*)d_ws;
  short* Kt  = Qt + (size_t)B_SZ * N_SP * K_INT;
  short* Gbf = Kt + (size_t)B_SZ * N_SP * K_INT;

  proj_kernel<<<B_SZ * NTILE, 256, 0, stream>>>(x, tw, tb, pw, pb, Qt, Kt, Gbf);
  attn_kernel<<<B_SZ * NTILE, 256, 0, stream>>>(Qt, Kt, Gbf, out);
}

// Round 17
// 394.083 us; speedup vs baseline: 1.0265x; 1.0265x over previous
//
#include <hip/hip_runtime.h>
#include <hip/hip_bf16.h>

#define B_SZ 16
#define C_IN 256
#define N_SP 2304
#define K_INT 128
#define NTILE 36   // q-tiles of 64
#define MT2 64     // attn m-tile per iteration
#define MITER2 36  // N_SP / MT2

typedef __attribute__((ext_vector_type(8))) short short8;
typedef __attribute__((ext_vector_type(4))) float f32x4;
typedef __attribute__((ext_vector_type(16))) float f32x16;

// packed fp32x2 -> bf16x2 (v_cvt_pk_bf16_f32, RNE)
__device__ inline unsigned pk_bf16(float a, float b) {
  float2 f; f.x = a; f.y = b;
  __hip_bfloat162 h = __float22bfloat162_rn(f);
  unsigned u;
  __builtin_memcpy(&u, &h, sizeof(u));
  return u;
}

// inline f32 weight row -> bf16 A-fragment (bit-identical to wcvt's RNE)
__device__ inline short8 ldw_bf16(const float* __restrict__ W, int k, int c0) {
  const float* wp = W + (size_t)k * C_IN + c0;
  float4 w0 = ((const float4*)wp)[0];
  float4 w1 = ((const float4*)wp)[1];
  unsigned u[4];
  u[0] = pk_bf16(w0.x, w0.y); u[1] = pk_bf16(w0.z, w0.w);
  u[2] = pk_bf16(w1.x, w1.y); u[3] = pk_bf16(w1.z, w1.w);
  short8 a;
  __builtin_memcpy(&a, u, sizeof(a));
  return a;
}

// ---------------------------------------------------------------------------
// Projection v8 (byte-identical to R14, passed at absmax 4.88e-4).
// ---------------------------------------------------------------------------
__global__ __launch_bounds__(256) void proj_kernel(
    const float* __restrict__ x,
    const float* __restrict__ theta_w, const float* __restrict__ theta_b,
    const float* __restrict__ phi_w,   const float* __restrict__ phi_b,
    short* __restrict__ Qt, short* __restrict__ Kt, short* __restrict__ Gbf)
{
  __shared__ __align__(16) char Xs[32768];  // [64 n][512 B] swizzled

  const int b  = blockIdx.x / NTILE;
  const int n0 = (blockIdx.x % NTILE) * 64;
  const int t  = threadIdx.x;
  const int wave = t >> 6, lane = t & 63;
  const int col = lane & 15, quad = lane >> 4;

  // ---- stage: coalesced loads, in-register 4x4 pack, b64 LDS writes ----
  {
    const int tq = t >> 4;   // c-row group
    const int a  = t & 15;   // n-segment (4 floats)
    const float* xs = x + ((size_t)b * C_IN + tq * 4) * N_SP + n0 + a * 4;
    short* gs = Gbf + ((size_t)b * C_IN + tq * 4) * N_SP + n0 + a * 4;
#pragma unroll
    for (int s = 0; s < 4; ++s) {  // c-base = s*64 + tq*4
      unsigned us[4][2];
#pragma unroll
      for (int r = 0; r < 4; ++r) {
        float4 v = *(const float4*)(xs + ((size_t)s * 64 + r) * N_SP);
        us[r][0] = pk_bf16(v.x, v.y);
        us[r][1] = pk_bf16(v.z, v.w);
        uint2 u; u.x = us[r][0]; u.y = us[r][1];
        *(uint2*)(gs + ((size_t)s * 64 + r) * N_SP) = u;
      }
      const int chunk = 8 * s + (tq >> 1);
      const int half8 = (tq & 1) * 8;
#pragma unroll
      for (int j = 0; j < 4; ++j) {
        const int w = j >> 1;
        unsigned w0, w1;
        if ((j & 1) == 0) {
          w0 = (us[0][w] & 0xffffu) | (us[1][w] << 16);
          w1 = (us[2][w] & 0xffffu) | (us[3][w] << 16);
        } else {
          w0 = (us[0][w] >> 16) | (us[1][w] & 0xffff0000u);
          w1 = (us[2][w] >> 16) | (us[3][w] & 0xffff0000u);
        }
        const int n = 4 * a + j;
        const int msk = (n ^ a) & 7;  // (n ^ (n>>2)) & 7
        uint2 u; u.x = w0; u.y = w1;
        *(uint2*)(Xs + n * 512 + ((chunk ^ msk) << 4) + half8) = u;
      }
    }
  }
  __syncthreads();

  // ---- GEMM: acc[p][kr][j] over 8 c-slices, weights converted inline ----
  f32x4 acc[2][2][4];
#pragma unroll
  for (int p = 0; p < 2; ++p)
#pragma unroll
    for (int kr = 0; kr < 2; ++kr)
#pragma unroll
      for (int j = 0; j < 4; ++j) {
        acc[p][kr][j][0] = 0.f; acc[p][kr][j][1] = 0.f;
        acc[p][kr][j][2] = 0.f; acc[p][kr][j][3] = 0.f;
      }

  int rmsk[4];
#pragma unroll
  for (int j = 0; j < 4; ++j) {
    const int n = 16 * j + col;
    rmsk[j] = (n ^ (n >> 2)) & 7;
  }

#pragma unroll
  for (int cs = 0; cs < 8; ++cs) {
    const int c0 = cs * 32;
    short8 afr[2][2];
#pragma unroll
    for (int p = 0; p < 2; ++p)
#pragma unroll
      for (int kr = 0; kr < 2; ++kr) {
        const int k = wave * 32 + kr * 16 + col;
        afr[p][kr] = ldw_bf16(p ? phi_w : theta_w, k, c0 + quad * 8);
      }
#pragma unroll
    for (int j = 0; j < 4; ++j) {
      const int chunk = 4 * cs + quad;
      short8 bfr = *(const short8*)(Xs + (16 * j + col) * 512 +
                                    ((chunk ^ rmsk[j]) << 4));
#pragma unroll
      for (int p = 0; p < 2; ++p)
#pragma unroll
        for (int kr = 0; kr < 2; ++kr)
          acc[p][kr][j] = __builtin_amdgcn_mfma_f32_16x16x32_bf16(
              afr[p][kr], bfr, acc[p][kr][j], 0, 0, 0);
    }
  }
  __syncthreads();  // Xs reads done; reuse as epilogue bounce buffer

  // ---- epilogue: bias, LDS bounce, coalesced b128 stores ----
  short* PB = (short*)Xs;  // [64 n][128 k] shorts, granule-swizzled
#pragma unroll
  for (int p = 0; p < 2; ++p) {
    const float* bias = p ? phi_b : theta_b;
    short* dst0 = p ? Kt : Qt;
#pragma unroll
    for (int kr = 0; kr < 2; ++kr) {
      const int k0 = wave * 32 + kr * 16 + quad * 4;
      float4 bv = *(const float4*)(bias + k0);
      const int g = wave * 8 + kr * 4 + quad;
#pragma unroll
      for (int j = 0; j < 4; ++j) {
        const int nloc = j * 16 + col;
        f32x4 v = acc[p][kr][j];
        uint2 sv;
        sv.x = pk_bf16(v[0] + bv.x, v[1] + bv.y);
        sv.y = pk_bf16(v[2] + bv.z, v[3] + bv.w);
        const int gp = g ^ (nloc & 7) ^ (((nloc >> 3) & 1) << 3);
        *(uint2*)(PB + nloc * 128 + gp * 4) = sv;
      }
    }
    __syncthreads();
    {
      const int nloc = t >> 2, kseg = t & 3;
      const int xb = ((nloc >> 3) & 1) << 3;
      uint2 r8[8];
#pragma unroll
      for (int i = 0; i < 8; ++i) {
        const int gp = (kseg * 8 + i) ^ (nloc & 7) ^ xb;
        r8[i] = *(const uint2*)(PB + nloc * 128 + gp * 4);
      }
      short* dst = dst0 + ((size_t)b * N_SP + n0 + nloc) * K_INT + kseg * 32;
#pragma unroll
      for (int i2 = 0; i2 < 4; ++i2) {
        uint4 u;
        u.x = r8[2 * i2].x;     u.y = r8[2 * i2].y;
        u.z = r8[2 * i2 + 1].x; u.w = r8[2 * i2 + 1].y;
        *(uint4*)(dst + i2 * 8) = u;
      }
    }
    __syncthreads();  // before p=1 overwrites PB
  }
}

// ---------------------------------------------------------------------------
// Flash attention v13: (q-half, c-half) wave decomposition, 32x32x16 MFMA.
// Wave w = (qh=w&1, ch=w>>1): computes S[32q x 64m] itself (2x-redundant QK)
// then PV for its own 128 c over all 64 m. P NEVER crosses waves (8 cvt_pk +
// 4 permlane32_swap in-register; semantics verified by lane-simulating the
// proven 16x16 code). l = lane-local VALU sum. ONLY shared state: K tile in
// LDS, 2-buffer, barrier scheme byte-patterned on R4's proven one.
// Fragment layouts (guide-verified 32x32): C/D col=lane&31,
// row=(reg&3)+8*(reg>>2)+4*(lane>>5); A row=lane&31, k=(lane>>5)*8+j; B
// col=lane&31, k=(lane>>5)*8+j. K swizzle chunk^((r&7)^((r>>3)&3)):
// enumerated uniform 8 lanes/bank-quad on stage-write AND QK-read.
// ---------------------------------------------------------------------------
__global__ __launch_bounds__(256) void attn_kernel(
    const short* __restrict__ Qt, const short* __restrict__ Kt,
    const short* __restrict__ Gbf, float* __restrict__ out)
{
  // loop: Kl[2][16384] in [0,32768). epilogue: Ybuf f32[128][68] in
  // [0,34816) + l/inv f32[64]+[64] at [34816,35328).
  __shared__ __align__(16) char smem[35328];

  const int b   = blockIdx.x / NTILE;
  const int qn0 = (blockIdx.x % NTILE) * 64;
  const int t = threadIdx.x;
  const int wave = t >> 6, lane = t & 63;
  const int l31 = lane & 31, lh = lane >> 5;
  const int qh = wave & 1, ch = wave >> 1;

  const short* Ktb = Kt  + (size_t)b * N_SP * K_INT;
  const short* Gb  = Gbf + (size_t)b * C_IN * N_SP;

  const float SC2 = 0.12754859f;  // (1/sqrt(128)) * log2(e)

  // ---- Q fragments (B-operand): Q[qn0+qh*32+l31][ks*16 + lh*8 + j] ----
  short8 qf[8];
  {
    const short* qb =
        Qt + ((size_t)b * N_SP + qn0 + qh * 32 + l31) * K_INT + lh * 8;
#pragma unroll
    for (int ks = 0; ks < 8; ++ks) qf[ks] = *(const short8*)(qb + ks * 16);
  }

  f32x16 yacc[4];
#pragma unroll
  for (int ct = 0; ct < 4; ++ct)
#pragma unroll
    for (int r = 0; r < 16; ++r) yacc[ct][r] = 0.f;
  float l_acc = 0.f;

  // ---- K LDS addrs: Kl[64 m][256 B], phys_chunk = chunk ^ msk(row),
  //      msk(r) = (r&7)^((r>>3)&3) ----
  const int krow = t >> 2, kcb = (t & 3) * 4;
  const int wmsk = (krow & 7) ^ ((krow >> 3) & 3);
  int KW[4];
#pragma unroll
  for (int i = 0; i < 4; ++i) KW[i] = krow * 256 + (((kcb + i) ^ wmsk) << 4);
  const int KG = krow * K_INT + (t & 3) * 32;  // shorts; + i*8 per chunk
  const int rmskr = (l31 & 7) ^ ((l31 >> 3) & 3);
  int KR[8];
#pragma unroll
  for (int ks = 0; ks < 8; ++ks)
    KR[ks] = l31 * 256 + (((ks * 2 + lh) ^ rmskr) << 4);

  // ---- G base: row c = ch*128 + ct*32 + l31; m-part it*64 + ks*16 + lh*8 ----
  const short* gptr = Gb + ((size_t)(ch * 128 + l31)) * N_SP + lh * 8;

  // ---- prologue: tile0 -> Kl[0]; kr <- tile1 ----
  short8 kr[4];
#pragma unroll
  for (int i = 0; i < 4; ++i) kr[i] = *(const short8*)(Ktb + KG + i * 8);
#pragma unroll
  for (int i = 0; i < 4; ++i) *(short8*)(smem + KW[i]) = kr[i];
#pragma unroll
  for (int i = 0; i < 4; ++i)
    kr[i] = *(const short8*)(Ktb + 8192 + KG + i * 8);
  __syncthreads();

  for (int it = 0; it < MITER2; ++it) {
    const int cur = it & 1;
    char* Klc = smem + cur * 16384;

    // ---- G loads for THIS iter (landed by the barrier's drain; PV after) --
    short8 g[4][4];
#pragma unroll
    for (int ct = 0; ct < 4; ++ct)
#pragma unroll
      for (int ks = 0; ks < 4; ++ks)
        g[ct][ks] = *(const short8*)(gptr + (size_t)ct * 32 * N_SP +
                                     it * 64 + ks * 16);

    // ---- QK: S[mt] (32q x 32m), A=K from LDS, B=Q regs; 16 MFMA ----
    f32x16 S0, S1;
#pragma unroll
    for (int r = 0; r < 16; ++r) { S0[r] = 0.f; S1[r] = 0.f; }
#pragma unroll
    for (int ks = 0; ks < 8; ++ks) {
      short8 a0 = *(const short8*)(Klc + KR[ks]);
      S0 = __builtin_amdgcn_mfma_f32_32x32x16_bf16(a0, qf[ks], S0, 0, 0, 0);
      short8 a1 = *(const short8*)(Klc + KR[ks] + 8192);
      S1 = __builtin_amdgcn_mfma_f32_32x32x16_bf16(a1, qf[ks], S1, 0, 0, 0);
    }

    // ---- softmax-lite in-place + lane-local l ----
#pragma unroll
    for (int r = 0; r < 16; ++r) {
      float p = exp2f(S0[r] * SC2); l_acc += p; S0[r] = p;
    }
#pragma unroll
    for (int r = 0; r < 16; ++r) {
      float p = exp2f(S1[r] * SC2); l_acc += p; S1[r] = p;
    }

    // ---- in-register P transpose to A-fragments: per 16-m slice,
    //      4 cvt_pk + 2 permlane32_swap ----
    short8 pa[4];
    {
      unsigned A0, A1, B0, B1;
      // slice 0: S0 regs 0..7
      A0 = pk_bf16(S0[0], S0[1]);  A1 = pk_bf16(S0[2], S0[3]);
      B0 = pk_bf16(S0[4], S0[5]);  B1 = pk_bf16(S0[6], S0[7]);
      asm("v_permlane32_swap_b32 %0, %1" : "+v"(A0), "+v"(B0));
      asm("v_permlane32_swap_b32 %0, %1" : "+v"(A1), "+v"(B1));
      { unsigned w[4] = {A0, A1, B0, B1}; __builtin_memcpy(&pa[0], w, 16); }
      // slice 1: S0 regs 8..15
      A0 = pk_bf16(S0[8], S0[9]);   A1 = pk_bf16(S0[10], S0[11]);
      B0 = pk_bf16(S0[12], S0[13]); B1 = pk_bf16(S0[14], S0[15]);
      asm("v_permlane32_swap_b32 %0, %1" : "+v"(A0), "+v"(B0));
      asm("v_permlane32_swap_b32 %0, %1" : "+v"(A1), "+v"(B1));
      { unsigned w[4] = {A0, A1, B0, B1}; __builtin_memcpy(&pa[1], w, 16); }
      // slice 2: S1 regs 0..7
      A0 = pk_bf16(S1[0], S1[1]);  A1 = pk_bf16(S1[2], S1[3]);
      B0 = pk_bf16(S1[4], S1[5]);  B1 = pk_bf16(S1[6], S1[7]);
      asm("v_permlane32_swap_b32 %0, %1" : "+v"(A0), "+v"(B0));
      asm("v_permlane32_swap_b32 %0, %1" : "+v"(A1), "+v"(B1));
      { unsigned w[4] = {A0, A1, B0, B1}; __builtin_memcpy(&pa[2], w, 16); }
      // slice 3: S1 regs 8..15
      A0 = pk_bf16(S1[8], S1[9]);   A1 = pk_bf16(S1[10], S1[11]);
      B0 = pk_bf16(S1[12], S1[13]); B1 = pk_bf16(S1[14], S1[15]);
      asm("v_permlane32_swap_b32 %0, %1" : "+v"(A0), "+v"(B0));
      asm("v_permlane32_swap_b32 %0, %1" : "+v"(A1), "+v"(B1));
      { unsigned w[4] = {A0, A1, B0, B1}; __builtin_memcpy(&pa[3], w, 16); }
    }

    // ---- K stage: tile it+1 -> Kl[cur^1] (kr loaded last iter: landed) ----
    if (it + 1 < MITER2) {
      char* Kln = smem + (cur ^ 1) * 16384;
#pragma unroll
      for (int i = 0; i < 4; ++i) *(short8*)(Kln + KW[i]) = kr[i];
    }
    // ---- K global prefetch: tile it+2 ----
    if (it + 2 < MITER2) {
      const short* kp = Ktb + (size_t)(it + 2) * 8192 + KG;
#pragma unroll
      for (int i = 0; i < 4; ++i) kr[i] = *(const short8*)(kp + i * 8);
    }
    __syncthreads();

    // ---- PV: Y[32q x 128c] += P G^T, registers only; m ascending ----
#pragma unroll
    for (int ct = 0; ct < 4; ++ct) {
      yacc[ct] = __builtin_amdgcn_mfma_f32_32x32x16_bf16(pa[0], g[ct][0],
                                                         yacc[ct], 0, 0, 0);
      yacc[ct] = __builtin_amdgcn_mfma_f32_32x32x16_bf16(pa[1], g[ct][1],
                                                         yacc[ct], 0, 0, 0);
      yacc[ct] = __builtin_amdgcn_mfma_f32_32x32x16_bf16(pa[2], g[ct][2],
                                                         yacc[ct], 0, 0, 0);
      yacc[ct] = __builtin_amdgcn_mfma_f32_32x32x16_bf16(pa[3], g[ct][3],
                                                         yacc[ct], 0, 0, 0);
    }
  }

  // ===================== epilogue =====================
  float* l_lds   = (float*)(smem + 34816);
  float* inv_lds = l_lds + 64;

  // l[q]: both lane-halves of a wave cover complementary m -> combine; waves
  // with same qh hold identical totals -> only ch==0 waves publish.
  float l_tot = l_acc + __shfl_xor(l_acc, 32);
  if (ch == 0 && lh == 0) l_lds[qh * 32 + l31] = l_tot;
  __syncthreads();
  if (t < 64) inv_lds[t] = 1.0f / l_lds[t];
  __syncthreads();

  // two rounds: ch==round waves bounce their normalized Y through LDS, then
  // all 256 threads store 128 contiguous bytes per (c, q-half).
  float* Ybuf = (float*)smem;  // [128 c][68] f32
#pragma unroll 1
  for (int round = 0; round < 2; ++round) {
    if (ch == round) {
#pragma unroll
      for (int ct = 0; ct < 4; ++ct)
#pragma unroll
        for (int r = 0; r < 16; ++r) {
          const int q = qh * 32 + (r & 3) + 8 * (r >> 2) + 4 * lh;
          Ybuf[(ct * 32 + l31) * 68 + q] = yacc[ct][r] * inv_lds[q];
        }
    }
    __syncthreads();
    {
      const int c = t >> 1, seg = (t & 1) * 32;
      float4 v[8];
#pragma unroll
      for (int i = 0; i < 8; ++i)
        v[i] = *(const float4*)&Ybuf[c * 68 + seg + i * 4];
      float* dst =
          out + ((size_t)b * C_IN + round * 128 + c) * N_SP + qn0 + seg;
#pragma unroll
      for (int i = 0; i < 8; ++i) *(float4*)(dst + i * 4) = v[i];
    }
    __syncthreads();
  }
}

extern "C" void kernel_launch(void* const* d_in, const int* in_sizes, int n_in,
                              void* d_out, int out_size, void* d_ws, size_t ws_size,
                              hipStream_t stream) {
  const float* x  = (const float*)d_in[0];
  const float* tw = (const float*)d_in[1];
  const float* tb = (const float*)d_in[2];
  const float* pw = (const float*)d_in[3];
  const float* pb = (const float*)d_in[4];
  float* out = (float*)d_out;

  // workspace: Qt (9.4MB) | Kt (9.4MB) | Gbf (18.9MB) = 37.75 MB total
  short* Qt  = (short*)d_ws;
  short* Kt  = Qt + (size_t)B_SZ * N_SP * K_INT;
  short* Gbf = Kt + (size_t)B_SZ * N_SP * K_INT;

  proj_kernel<<<B_SZ * NTILE, 256, 0, stream>>>(x, tw, tb, pw, pb, Qt, Kt, Gbf);
  attn_kernel<<<B_SZ * NTILE, 256, 0, stream>>>(Qt, Kt, Gbf, out);
}

// Round 18
// 240.429 us; speedup vs baseline: 1.6826x; 1.6391x over previous
//
#include <hip/hip_runtime.h>
#include <hip/hip_bf16.h>

#define B_SZ 16
#define C_IN 256
#define N_SP 2304
#define K_INT 128
#define NTILE 36  // q-tiles of 64
#define MT 32     // key/value m-tile
#define MITER 72  // N_SP / MT

typedef __attribute__((ext_vector_type(8))) short short8;
typedef __attribute__((ext_vector_type(4))) float f32x4;

// bf16 weights, converted once by wcvt_kernel: [p][k][c], p=0 theta, p=1 phi
__device__ __align__(16) short g_Wbf[2 * K_INT * C_IN];

// packed fp32x2 -> bf16x2 (v_cvt_pk_bf16_f32, RNE)
__device__ inline unsigned pk_bf16(float a, float b) {
  float2 f; f.x = a; f.y = b;
  __hip_bfloat162 h = __float22bfloat162_rn(f);
  unsigned u;
  __builtin_memcpy(&u, &h, sizeof(u));
  return u;
}

// ---------------------------------------------------------------------------
// One-time weight convert: f32 -> bf16 into g_Wbf (128 KiB, L2-resident).
// (R14 A/B: hoisted conversion beats inline by ~7us -- keep the split.)
// ---------------------------------------------------------------------------
__global__ __launch_bounds__(256) void wcvt_kernel(
    const float* __restrict__ tw, const float* __restrict__ pw)
{
  const int i = (blockIdx.x * 256 + threadIdx.x) * 4;  // grid 32 covers 32768
  float4 a = *(const float4*)(tw + i);
  float4 p = *(const float4*)(pw + i);
  uint2 ua; ua.x = pk_bf16(a.x, a.y); ua.y = pk_bf16(a.z, a.w);
  uint2 up; up.x = pk_bf16(p.x, p.y); up.y = pk_bf16(p.z, p.w);
  *(uint2*)(g_Wbf + i) = ua;
  *(uint2*)(g_Wbf + 32768 + i) = up;
}

// ---------------------------------------------------------------------------
// Projection v7 (best measured): coalesced 4cx4n micro-tile stage ->
// in-register pack -> 16 ds_write_b64; pad-free swizzled Xs; weight
// fragments double-buffered; epilogue LDS-bounce -> 256B-contiguous b128
// stores. Verified absmax 4.882812e-4 (R11/R12).
// ---------------------------------------------------------------------------
__global__ __launch_bounds__(256) void proj_kernel(
    const float* __restrict__ x,
    const float* __restrict__ theta_b, const float* __restrict__ phi_b,
    short* __restrict__ Qt, short* __restrict__ Kt, short* __restrict__ Gbf)
{
  __shared__ __align__(16) char Xs[32768];  // [64 n][512 B] swizzled

  const int b  = blockIdx.x / NTILE;
  const int n0 = (blockIdx.x % NTILE) * 64;
  const int t  = threadIdx.x;
  const int wave = t >> 6, lane = t & 63;
  const int col = lane & 15, quad = lane >> 4;

  // ---- weight prefetch for cs=0 (lands during stage) ----
  short8 afr[2][2][2];  // [buf][p][kr]
#pragma unroll
  for (int p = 0; p < 2; ++p)
#pragma unroll
    for (int kr = 0; kr < 2; ++kr) {
      const int k = wave * 32 + kr * 16 + col;
      afr[0][p][kr] = *(const short8*)(g_Wbf + p * 32768 + k * C_IN + quad * 8);
    }

  // ---- stage: coalesced loads, in-register 4x4 pack, b64 LDS writes ----
  {
    const int tq = t >> 4;   // c-row group
    const int a  = t & 15;   // n-segment (4 floats)
    const float* xs = x + ((size_t)b * C_IN + tq * 4) * N_SP + n0 + a * 4;
    short* gs = Gbf + ((size_t)b * C_IN + tq * 4) * N_SP + n0 + a * 4;
#pragma unroll
    for (int s = 0; s < 4; ++s) {  // c-base = s*64 + tq*4
      unsigned us[4][2];
#pragma unroll
      for (int r = 0; r < 4; ++r) {
        float4 v = *(const float4*)(xs + ((size_t)s * 64 + r) * N_SP);
        us[r][0] = pk_bf16(v.x, v.y);
        us[r][1] = pk_bf16(v.z, v.w);
        uint2 u; u.x = us[r][0]; u.y = us[r][1];
        *(uint2*)(gs + ((size_t)s * 64 + r) * N_SP) = u;
      }
      const int chunk = 8 * s + (tq >> 1);
      const int half8 = (tq & 1) * 8;
#pragma unroll
      for (int j = 0; j < 4; ++j) {
        const int w = j >> 1;
        unsigned w0, w1;
        if ((j & 1) == 0) {
          w0 = (us[0][w] & 0xffffu) | (us[1][w] << 16);
          w1 = (us[2][w] & 0xffffu) | (us[3][w] << 16);
        } else {
          w0 = (us[0][w] >> 16) | (us[1][w] & 0xffff0000u);
          w1 = (us[2][w] >> 16) | (us[3][w] & 0xffff0000u);
        }
        const int n = 4 * a + j;
        const int msk = (n ^ a) & 7;  // (n ^ (n>>2)) & 7
        uint2 u; u.x = w0; u.y = w1;
        *(uint2*)(Xs + n * 512 + ((chunk ^ msk) << 4) + half8) = u;
      }
    }
  }
  __syncthreads();

  // ---- GEMM: acc[p][kr][j] over 8 c-slices, weights dbuf'd ----
  f32x4 acc[2][2][4];
#pragma unroll
  for (int p = 0; p < 2; ++p)
#pragma unroll
    for (int kr = 0; kr < 2; ++kr)
#pragma unroll
      for (int j = 0; j < 4; ++j) {
        acc[p][kr][j][0] = 0.f; acc[p][kr][j][1] = 0.f;
        acc[p][kr][j][2] = 0.f; acc[p][kr][j][3] = 0.f;
      }

  // read-side swizzle masks per j (n = 16j + col)
  int rmsk[4];
#pragma unroll
  for (int j = 0; j < 4; ++j) {
    const int n = 16 * j + col;
    rmsk[j] = (n ^ (n >> 2)) & 7;
  }

#pragma unroll
  for (int cs = 0; cs < 8; ++cs) {
    const int cur = cs & 1, nxt = cur ^ 1;
    if (cs + 1 < 8) {
      const int c0n = (cs + 1) * 32;
#pragma unroll
      for (int p = 0; p < 2; ++p)
#pragma unroll
        for (int kr = 0; kr < 2; ++kr) {
          const int k = wave * 32 + kr * 16 + col;
          afr[nxt][p][kr] =
              *(const short8*)(g_Wbf + p * 32768 + k * C_IN + c0n + quad * 8);
        }
    }
#pragma unroll
    for (int j = 0; j < 4; ++j) {
      const int chunk = 4 * cs + quad;
      short8 bfr = *(const short8*)(Xs + (16 * j + col) * 512 +
                                    ((chunk ^ rmsk[j]) << 4));
#pragma unroll
      for (int p = 0; p < 2; ++p)
#pragma unroll
        for (int kr = 0; kr < 2; ++kr)
          acc[p][kr][j] = __builtin_amdgcn_mfma_f32_16x16x32_bf16(
              afr[cur][p][kr], bfr, acc[p][kr][j], 0, 0, 0);
    }
  }
  __syncthreads();  // Xs reads done; reuse as epilogue bounce buffer

  // ---- epilogue: bias, LDS bounce, coalesced b128 stores ----
  short* PB = (short*)Xs;  // [64 n][128 k] shorts, granule-swizzled
#pragma unroll
  for (int p = 0; p < 2; ++p) {
    const float* bias = p ? phi_b : theta_b;
    short* dst0 = p ? Kt : Qt;
#pragma unroll
    for (int kr = 0; kr < 2; ++kr) {
      const int k0 = wave * 32 + kr * 16 + quad * 4;
      float4 bv = *(const float4*)(bias + k0);
      const int g = wave * 8 + kr * 4 + quad;
#pragma unroll
      for (int j = 0; j < 4; ++j) {
        const int nloc = j * 16 + col;
        f32x4 v = acc[p][kr][j];
        uint2 sv;
        sv.x = pk_bf16(v[0] + bv.x, v[1] + bv.y);
        sv.y = pk_bf16(v[2] + bv.z, v[3] + bv.w);
        const int gp = g ^ (nloc & 7) ^ (((nloc >> 3) & 1) << 3);
        *(uint2*)(PB + nloc * 128 + gp * 4) = sv;
      }
    }
    __syncthreads();
    {
      const int nloc = t >> 2, kseg = t & 3;
      const int xb = ((nloc >> 3) & 1) << 3;
      uint2 r8[8];
#pragma unroll
      for (int i = 0; i < 8; ++i) {
        const int gp = (kseg * 8 + i) ^ (nloc & 7) ^ xb;
        r8[i] = *(const uint2*)(PB + nloc * 128 + gp * 4);
      }
      short* dst = dst0 + ((size_t)b * N_SP + n0 + nloc) * K_INT + kseg * 32;
#pragma unroll
      for (int i2 = 0; i2 < 4; ++i2) {
        uint4 u;
        u.x = r8[2 * i2].x;     u.y = r8[2 * i2].y;
        u.z = r8[2 * i2 + 1].x; u.w = r8[2 * i2 + 1].y;
        *(uint4*)(dst + i2 * 8) = u;
      }
    }
    __syncthreads();  // before p=1 overwrites PB
  }
}

// ---------------------------------------------------------------------------
// Flash attention = R4-EXACT. 147us, absmax 4.88e-4, passed 5x. This is a
// robust local optimum: 13 structural variants (block size, m-tile, barrier
// semantics, prefetch placement, K-direct, deferred-PV, wave decomposition)
// all measured >=147us or failed correctness. The cost is the barrier-locked
// per-iter chain, not any pipe roofline; schedules that attack it either
// re-serialize elsewhere, lose occupancy, or need hand-rolled sync that
// proved unverifiable in this harness (R10/R13/R16).
// ---------------------------------------------------------------------------
__global__ __launch_bounds__(256) void attn_kernel(
    const short* __restrict__ Qt, const short* __restrict__ Kt,
    const short* __restrict__ Gbf, float* __restrict__ out)
{
  __shared__ __align__(16) char Kl[2][8192];          // [buf][32 m][128 k] swz
  __shared__ __align__(16) short Pblob[2][4][64][8];  // [buf][wave][lane][8]
  __shared__ float l_lds[64];

  const int b   = blockIdx.x / NTILE;
  const int qn0 = (blockIdx.x % NTILE) * 64;
  const int t = threadIdx.x;
  const int wave = t >> 6, lane = t & 63;
  const int col = lane & 15, quad = lane >> 4;

  const short* Ktb = Kt  + (size_t)b * N_SP * K_INT;
  const short* Gb  = Gbf + (size_t)b * C_IN * N_SP;

  // Q fragments in registers for the whole loop (B-operand layout: col=q)
  short8 qf[4];
  {
    const short* qb = Qt + ((size_t)b * N_SP + qn0 + wave * 16 + col) * K_INT + quad * 8;
#pragma unroll
    for (int kk = 0; kk < 4; ++kk) qf[kk] = *(const short8*)(qb + kk * 32);
  }

  f32x4 yacc[4][4];  // [q-tile][c-tile]
#pragma unroll
  for (int i = 0; i < 4; ++i)
#pragma unroll
    for (int j = 0; j < 4; ++j) {
      yacc[i][j][0] = 0.f; yacc[i][j][1] = 0.f;
      yacc[i][j][2] = 0.f; yacc[i][j][3] = 0.f;
    }
  f32x4 lacc;
  lacc[0] = 0.f; lacc[1] = 0.f; lacc[2] = 0.f; lacc[3] = 0.f;

  short8 ones;
#pragma unroll
  for (int j = 0; j < 8; ++j) ones[j] = (short)0x3F80;  // bf16 1.0

  const float SC2 = 0.12754859f;  // (1/sqrt(128)) * log2(e)

  // ---- K LDS offsets: phys(r,chunk) = r*256 + ((chunk ^ (r&7))<<4) ----
  const int KW = (t >> 4) * 256 + ((((t & 15) ^ ((t >> 4) & 7))) << 4);
  int KR0[4];
#pragma unroll
  for (int kk = 0; kk < 4; ++kk)
    KR0[kk] = col * 256 + ((((kk << 2) + quad) ^ (col & 7)) << 4);

  // ---- global offsets ----
  const int koff = (t >> 4) * K_INT + (t & 15) * 8;  // K stage rows t>>4 / +16
  const short* gbase = Gb + ((size_t)(wave * 64 + col)) * N_SP + quad * 8;

  // ---- prologue: tile0 -> Kl[0]; kr <- tile1; gA <- G tile0 ----
  short8 krA, krB;
  krA = *(const short8*)(Ktb + koff);
  krB = *(const short8*)(Ktb + 2048 + koff);
  *(short8*)(Kl[0] + KW) = krA;
  *(short8*)(Kl[0] + KW + 4096) = krB;
  krA = *(const short8*)(Ktb + 4096 + koff);
  krB = *(const short8*)(Ktb + 6144 + koff);
  short8 gA[4], gB[4];
#pragma unroll
  for (int ct = 0; ct < 4; ++ct)
    gA[ct] = *(const short8*)(gbase + (size_t)ct * 16 * N_SP);
  __syncthreads();

#define SUBITER(MTV, CUR, GC, GN)                                              \
  {                                                                            \
    /* 1. QK: S = K(tile MTV) x Q  (A-frags from LDS) */                       \
    f32x4 s0, s1;                                                              \
    s0[0] = 0.f; s0[1] = 0.f; s0[2] = 0.f; s0[3] = 0.f;                        \
    s1[0] = 0.f; s1[1] = 0.f; s1[2] = 0.f; s1[3] = 0.f;                        \
    _Pragma("unroll")                                                          \
    for (int kk = 0; kk < 4; ++kk) {                                           \
      short8 a0 = *(const short8*)(Kl[CUR] + KR0[kk]);                         \
      s0 = __builtin_amdgcn_mfma_f32_16x16x32_bf16(a0, qf[kk], s0, 0, 0, 0);   \
      short8 a1 = *(const short8*)(Kl[CUR] + KR0[kk] + 4096);                  \
      s1 = __builtin_amdgcn_mfma_f32_16x16x32_bf16(a1, qf[kk], s1, 0, 0, 0);   \
    }                                                                          \
    /* 2. softmax-lite + in-register transpose to A-fragment */                \
    unsigned u0 = pk_bf16(exp2f(s0[0] * SC2), exp2f(s0[1] * SC2));             \
    unsigned u1 = pk_bf16(exp2f(s0[2] * SC2), exp2f(s0[3] * SC2));             \
    unsigned u2 = pk_bf16(exp2f(s1[0] * SC2), exp2f(s1[1] * SC2));             \
    unsigned u3 = pk_bf16(exp2f(s1[2] * SC2), exp2f(s1[3] * SC2));             \
    asm("v_permlane32_swap_b32 %0, %1" : "+v"(u0), "+v"(u2));                  \
    asm("v_permlane32_swap_b32 %0, %1" : "+v"(u1), "+v"(u3));                  \
    asm("v_permlane16_swap_b32 %0, %1" : "+v"(u0), "+v"(u2));                  \
    asm("v_permlane16_swap_b32 %0, %1" : "+v"(u1), "+v"(u3));                  \
    unsigned uu[4] = {u0, u1, u2, u3};                                         \
    short8 pa; __builtin_memcpy(&pa, uu, 16);                                  \
    lacc = __builtin_amdgcn_mfma_f32_16x16x32_bf16(pa, ones, lacc, 0, 0, 0);   \
    /* 3. P exchange write (lane-linear, conflict-free) */                     \
    *(short8*)&Pblob[CUR][wave][lane][0] = pa;                                 \
    /* 4. K stage: tile MTV+1 -> Kl[CUR^1] (kr loaded LAST iter: landed) */    \
    if ((MTV) + 1 < MITER) {                                                   \
      *(short8*)(Kl[(CUR) ^ 1] + KW) = krA;                                    \
      *(short8*)(Kl[(CUR) ^ 1] + KW + 4096) = krB;                             \
    }                                                                          \
    /* 5. K global prefetch: tile MTV+2 (staged next iter) */                  \
    if ((MTV) + 2 < MITER) {                                                   \
      const short* kp = Ktb + (size_t)((MTV) + 2) * 4096 + koff;               \
      krA = *(const short8*)(kp);                                              \
      krB = *(const short8*)(kp + 2048);                                       \
    }                                                                          \
    /* 6. G global prefetch: tile MTV+1 (consumed next iter's PV) */           \
    if ((MTV) + 1 < MITER) {                                                   \
      _Pragma("unroll")                                                        \
      for (int ct = 0; ct < 4; ++ct)                                           \
        GN[ct] = *(const short8*)(gbase + (size_t)ct * 16 * N_SP +             \
                                  ((MTV) + 1) * 32);                           \
    }                                                                          \
    __syncthreads();                                                           \
    /* 7. PV: Y[q][c] += P[q][m] G^T[m][c]  (G regs, P lane-linear) */         \
    _Pragma("unroll")                                                          \
    for (int qt = 0; qt < 4; ++qt) {                                           \
      short8 paq = *(const short8*)&Pblob[CUR][qt][lane][0];                   \
      _Pragma("unroll")                                                        \
      for (int ct = 0; ct < 4; ++ct)                                           \
        yacc[qt][ct] = __builtin_amdgcn_mfma_f32_16x16x32_bf16(                \
            paq, GC[ct], yacc[qt][ct], 0, 0, 0);                               \
    }                                                                          \
  }

  for (int mt2 = 0; mt2 < MITER / 2; ++mt2) {
    SUBITER(2 * mt2,     0, gA, gB)
    SUBITER(2 * mt2 + 1, 1, gB, gA)
  }
#undef SUBITER

  // ---- l exchange: wave w holds l[16w + quad*4 + r] in lacc[r] ----
  if (col == 0) {
#pragma unroll
    for (int r = 0; r < 4; ++r) l_lds[wave * 16 + quad * 4 + r] = lacc[r];
  }
  __syncthreads();

  // ---- epilogue: normalize and store out[b][c][n]; c = wave*64+ct*16+col ----
#pragma unroll
  for (int qt = 0; qt < 4; ++qt) {
    float4 lq = *(const float4*)&l_lds[qt * 16 + quad * 4];
    float4 iv;
    iv.x = 1.0f / lq.x; iv.y = 1.0f / lq.y; iv.z = 1.0f / lq.z; iv.w = 1.0f / lq.w;
    const int nb = qn0 + qt * 16 + quad * 4;
#pragma unroll
    for (int ct = 0; ct < 4; ++ct) {
      const int c = wave * 64 + ct * 16 + col;
      f32x4 v = yacc[qt][ct];
      float4 o;
      o.x = v[0] * iv.x; o.y = v[1] * iv.y; o.z = v[2] * iv.z; o.w = v[3] * iv.w;
      *(float4*)(out + ((size_t)b * C_IN + c) * N_SP + nb) = o;
    }
  }
}

extern "C" void kernel_launch(void* const* d_in, const int* in_sizes, int n_in,
                              void* d_out, int out_size, void* d_ws, size_t ws_size,
                              hipStream_t stream) {
  const float* x  = (const float*)d_in[0];
  const float* tw = (const float*)d_in[1];
  const float* tb = (const float*)d_in[2];
  const float* pw = (const float*)d_in[3];
  const float* pb = (const float*)d_in[4];
  float* out = (float*)d_out;

  // workspace: Qt (9.4MB) | Kt (9.4MB) | Gbf (18.9MB) = 37.75 MB total
  short* Qt  = (short*)d_ws;
  short* Kt  = Qt + (size_t)B_SZ * N_SP * K_INT;
  short* Gbf = Kt + (size_t)B_SZ * N_SP * K_INT;

  wcvt_kernel<<<32, 256, 0, stream>>>(tw, pw);
  proj_kernel<<<B_SZ * NTILE, 256, 0, stream>>>(x, tb, pb, Qt, Kt, Gbf);
  attn_kernel<<<B_SZ * NTILE, 256, 0, stream>>>(Qt, Kt, Gbf, out);
}